// Round 1
// baseline (1209.091 us; speedup 1.0000x reference)
//
#include <hip/hip_runtime.h>
#include <math.h>

#define B 256
#define N 1000
#define D 256
#define H 8
#define DH 32
#define NEG (-1000000000.0f)

__device__ __forceinline__ float waveReduceMax(float v) {
#pragma unroll
    for (int off = 32; off >= 1; off >>= 1) v = fmaxf(v, __shfl_xor(v, off, 64));
    return v;
}
__device__ __forceinline__ float waveReduceSum(float v) {
#pragma unroll
    for (int off = 32; off >= 1; off >>= 1) v += __shfl_xor(v, off, 64);
    return v;
}

// ---------------------------------------------------------------------------
// K1: mask fix + step_context = [cur, graph_ctx, dyn] @ W_ctx  (515 x 512)
// grid 64 blocks x 4 batches, 256 threads
// ---------------------------------------------------------------------------
__global__ __launch_bounds__(256) void k_ctx(
    const float* __restrict__ ne, const float* __restrict__ gc,
    const float* __restrict__ cap, const float* __restrict__ dem,
    const float* __restrict__ rem, const float* __restrict__ Wctx,
    const int* __restrict__ head, const int* __restrict__ feas,
    int* __restrict__ mask_ws, float* __restrict__ q1_ws,
    float* __restrict__ q2_ws)
{
    __shared__ float xs[4][515];
    __shared__ int sRed[4];
    __shared__ int sAny;
    const int tid = threadIdx.x;
    const int b0 = blockIdx.x * 4;

    // --- mask: mask[:,0] |= !any(mask) ---
    for (int bb = 0; bb < 4; ++bb) {
        const int b = b0 + bb;
        int vals[4];
        int orloc = 0;
#pragma unroll
        for (int k = 0; k < 4; ++k) {
            int n = tid + k * 256;
            int v = 0;
            if (n < N) v = feas[b * N + n];
            vals[k] = v;
            orloc |= v;
        }
#pragma unroll
        for (int off = 32; off >= 1; off >>= 1) orloc |= __shfl_xor(orloc, off, 64);
        if ((tid & 63) == 0) sRed[tid >> 6] = orloc;
        __syncthreads();
        if (tid == 0) sAny = sRed[0] | sRed[1] | sRed[2] | sRed[3];
        __syncthreads();
        const int anyf = sAny;
#pragma unroll
        for (int k = 0; k < 4; ++k) {
            int n = tid + k * 256;
            if (n < N) {
                int m = vals[k];
                if (n == 0 && !anyf) m = 1;
                mask_ws[b * N + n] = m;
            }
        }
        __syncthreads();
    }

    // --- load x rows into LDS ---
    for (int bb = 0; bb < 4; ++bb) {
        const int b = b0 + bb;
        const int hd = head[b];
        for (int i = tid; i < 515; i += 256) {
            float v;
            if (i < 256)       v = ne[(size_t)(b * N + hd) * D + i];
            else if (i < 512)  v = gc[b * D + (i - 256)];
            else if (i == 512) v = cap[b];
            else if (i == 513) v = dem[b];
            else               v = rem[b];
            xs[bb][i] = v;
        }
    }
    __syncthreads();

    // --- matmul: each thread computes cols j (q1) and j+256 (q2) for 4 batches
    const int j = tid;
    float a0[4] = {0.f, 0.f, 0.f, 0.f}, a1[4] = {0.f, 0.f, 0.f, 0.f};
    for (int i = 0; i < 515; ++i) {
        float w0 = Wctx[i * 512 + j];
        float w1 = Wctx[i * 512 + 256 + j];
#pragma unroll
        for (int bb = 0; bb < 4; ++bb) {
            a0[bb] = fmaf(xs[bb][i], w0, a0[bb]);
            a1[bb] = fmaf(xs[bb][i], w1, a1[bb]);
        }
    }
#pragma unroll
    for (int bb = 0; bb < 4; ++bb) {
        q1_ws[(b0 + bb) * D + j] = a0[bb];
        q2_ws[(b0 + bb) * D + j] = a1[bb];
    }
}

// ---------------------------------------------------------------------------
// K2: dual-query masked attention per (b,h). Reads K once, V once.
// grid B*H = 2048 blocks, 256 threads
// ---------------------------------------------------------------------------
__global__ __launch_bounds__(256) void k_attn(
    const float* __restrict__ gk, const float* __restrict__ gv,
    const float* __restrict__ q1_ws, const float* __restrict__ q2_ws,
    const int* __restrict__ mask_ws,
    float* __restrict__ out1_ws, float* __restrict__ out2_ws)
{
    __shared__ float s1[N];
    __shared__ float s2[N];
    __shared__ __align__(16) float qsh[2][DH];
    __shared__ float redA[4], redB[4];
    __shared__ float part[2][4][DH];

    const int tid = threadIdx.x;
    const int b = blockIdx.x >> 3;
    const int h = blockIdx.x & 7;

    if (tid < 64) {
        int set = tid >> 5, d = tid & 31;
        const float* q = set ? q2_ws : q1_ws;
        qsh[set][d] = q[b * D + h * DH + d];
    }
    __syncthreads();

    float4 q1v[8], q2v[8];
#pragma unroll
    for (int k = 0; k < 8; ++k) {
        q1v[k] = ((const float4*)qsh[0])[k];
        q2v[k] = ((const float4*)qsh[1])[k];
    }

    const float scale = 0.17677669529663687f; // 1/sqrt(32)
    const float4* kbase = (const float4*)(gk + (size_t)(b * H + h) * N * DH);
    float m1 = -INFINITY, m2 = -INFINITY;

#pragma unroll
    for (int n0 = 0; n0 < N; n0 += 256) {
        int n = n0 + tid;
        if (n < N) {
            const float4* kp = kbase + n * 8;
            float d1 = 0.f, d2 = 0.f;
#pragma unroll
            for (int k = 0; k < 8; ++k) {
                float4 kv = kp[k];
                d1 += kv.x * q1v[k].x + kv.y * q1v[k].y + kv.z * q1v[k].z + kv.w * q1v[k].w;
                d2 += kv.x * q2v[k].x + kv.y * q2v[k].y + kv.z * q2v[k].z + kv.w * q2v[k].w;
            }
            int m = mask_ws[b * N + n];
            float v1 = m ? d1 * scale : NEG;
            float v2 = m ? d2 * scale : NEG;
            s1[n] = v1;
            s2[n] = v2;
            m1 = fmaxf(m1, v1);
            m2 = fmaxf(m2, v2);
        }
    }

    // block-reduce max (both sets)
    m1 = waveReduceMax(m1);
    m2 = waveReduceMax(m2);
    if ((tid & 63) == 0) { redA[tid >> 6] = m1; redB[tid >> 6] = m2; }
    __syncthreads();
    m1 = fmaxf(fmaxf(redA[0], redA[1]), fmaxf(redA[2], redA[3]));
    m2 = fmaxf(fmaxf(redB[0], redB[1]), fmaxf(redB[2], redB[3]));
    __syncthreads(); // before reusing redA/redB for sums

    float sum1 = 0.f, sum2 = 0.f;
#pragma unroll
    for (int n0 = 0; n0 < N; n0 += 256) {
        int n = n0 + tid;
        if (n < N) {
            float e1 = __expf(s1[n] - m1);
            float e2 = __expf(s2[n] - m2);
            s1[n] = e1;
            s2[n] = e2;
            sum1 += e1;
            sum2 += e2;
        }
    }
    sum1 = waveReduceSum(sum1);
    sum2 = waveReduceSum(sum2);
    if ((tid & 63) == 0) { redA[tid >> 6] = sum1; redB[tid >> 6] = sum2; }
    __syncthreads();
    sum1 = redA[0] + redA[1] + redA[2] + redA[3];
    sum2 = redB[0] + redB[1] + redB[2] + redB[3];

    // V pass: thread -> (set, chunk, dh). 4 n-chunks interleaved for coalescing.
    const int set = tid >> 7, r = tid & 127, dh = r & 31, c = r >> 5;
    const float* vb = gv + (size_t)(b * H + h) * N * DH;
    const float* sp = set ? s2 : s1;
    float acc = 0.f;
    for (int n = c; n < N; n += 4) {
        acc = fmaf(sp[n], vb[n * DH + dh], acc);
    }
    part[set][c][dh] = acc;
    __syncthreads();

    if (tid < 64) {
        int st = tid >> 5, d = tid & 31;
        float tot = part[st][0][d] + part[st][1][d] + part[st][2][d] + part[st][3][d];
        float rs = 1.f / (st ? sum2 : sum1);
        float* o = st ? out2_ws : out1_ws;
        o[b * D + h * DH + d] = tot * rs;
    }
}

// ---------------------------------------------------------------------------
// K3: glimpse = out1 @ W_out ; head_encoding = out2 @ W_sa
// grid 64 blocks x 4 batches, 256 threads
// ---------------------------------------------------------------------------
__global__ __launch_bounds__(256) void k_proj(
    const float* __restrict__ out1_ws, const float* __restrict__ out2_ws,
    const float* __restrict__ Wout, const float* __restrict__ Wsa,
    float* __restrict__ glimpse_ws, float* __restrict__ head_enc)
{
    __shared__ float x1[4][D];
    __shared__ float x2[4][D];
    const int tid = threadIdx.x;
    const int b0 = blockIdx.x * 4;
#pragma unroll
    for (int bb = 0; bb < 4; ++bb) {
        x1[bb][tid] = out1_ws[(b0 + bb) * D + tid];
        x2[bb][tid] = out2_ws[(b0 + bb) * D + tid];
    }
    __syncthreads();
    float ag[4] = {0.f, 0.f, 0.f, 0.f}, as_[4] = {0.f, 0.f, 0.f, 0.f};
    for (int i = 0; i < D; ++i) {
        float w0 = Wout[i * D + tid];
        float w1 = Wsa[i * D + tid];
#pragma unroll
        for (int bb = 0; bb < 4; ++bb) {
            ag[bb] = fmaf(x1[bb][i], w0, ag[bb]);
            as_[bb] = fmaf(x2[bb][i], w1, as_[bb]);
        }
    }
#pragma unroll
    for (int bb = 0; bb < 4; ++bb) {
        glimpse_ws[(b0 + bb) * D + tid] = ag[bb];
        head_enc[(b0 + bb) * D + tid] = as_[bb];
    }
}

// ---------------------------------------------------------------------------
// K4: logits[b,n] = mask ? 10*tanh(dot(glimpse, logit_key[b,n,:])/16) : NEG
// wave-per-row GEMV; grid B*4 blocks (250 rows each), 256 threads (4 waves)
// ---------------------------------------------------------------------------
__global__ __launch_bounds__(256) void k_logits(
    const float* __restrict__ lk, const float* __restrict__ glimpse_ws,
    const int* __restrict__ mask_ws, float* __restrict__ logits_ws)
{
    __shared__ __align__(16) float gsh[D];
    const int tid = threadIdx.x;
    const int b = blockIdx.x >> 2;
    const int chunk = blockIdx.x & 3;
    gsh[tid] = glimpse_ws[b * D + tid];
    __syncthreads();

    const int lane = tid & 63, wid = tid >> 6;
    float4 gv = ((const float4*)gsh)[lane];
    const int n0 = chunk * 250;
    for (int n = n0 + wid; n < n0 + 250; n += 4) {
        float4 kv = ((const float4*)(lk + (size_t)(b * N + n) * D))[lane];
        float p = kv.x * gv.x + kv.y * gv.y + kv.z * gv.z + kv.w * gv.w;
#pragma unroll
        for (int off = 32; off >= 1; off >>= 1) p += __shfl_xor(p, off, 64);
        if (lane == 0) {
            float s = p * 0.0625f; // 1/sqrt(256)
            float l = 10.0f * tanhf(s);
            logits_ws[b * N + n] = mask_ws[b * N + n] ? l : NEG;
        }
    }
}

// ---------------------------------------------------------------------------
// K5: log_softmax over each row of logits
// grid B blocks, 256 threads
// ---------------------------------------------------------------------------
__global__ __launch_bounds__(256) void k_logsoftmax(
    const float* __restrict__ logits_ws, float* __restrict__ logp)
{
    __shared__ float red[4];
    const int tid = threadIdx.x;
    const int b = blockIdx.x;
    float v[4];
    float m = -INFINITY;
#pragma unroll
    for (int k = 0; k < 4; ++k) {
        int n = tid + k * 256;
        v[k] = (n < N) ? logits_ws[b * N + n] : -INFINITY;
        m = fmaxf(m, v[k]);
    }
    m = waveReduceMax(m);
    if ((tid & 63) == 0) red[tid >> 6] = m;
    __syncthreads();
    m = fmaxf(fmaxf(red[0], red[1]), fmaxf(red[2], red[3]));
    __syncthreads();
    float s = 0.f;
#pragma unroll
    for (int k = 0; k < 4; ++k) {
        int n = tid + k * 256;
        if (n < N) s += __expf(v[k] - m);
    }
    s = waveReduceSum(s);
    if ((tid & 63) == 0) red[tid >> 6] = s;
    __syncthreads();
    s = red[0] + red[1] + red[2] + red[3];
    const float lse = m + logf(s);
#pragma unroll
    for (int k = 0; k < 4; ++k) {
        int n = tid + k * 256;
        if (n < N) logp[b * N + n] = v[k] - lse;
    }
}

extern "C" void kernel_launch(void* const* d_in, const int* in_sizes, int n_in,
                              void* d_out, int out_size, void* d_ws, size_t ws_size,
                              hipStream_t stream) {
    const float* ne   = (const float*)d_in[0];
    const float* gc   = (const float*)d_in[1];
    const float* gk   = (const float*)d_in[2];
    const float* gvv  = (const float*)d_in[3];
    const float* lk   = (const float*)d_in[4];
    const float* cap  = (const float*)d_in[5];
    const float* dem  = (const float*)d_in[6];
    const float* rem  = (const float*)d_in[7];
    const float* Wctx = (const float*)d_in[8];
    const float* Wout = (const float*)d_in[9];
    const float* Wsa  = (const float*)d_in[10];
    const int*   head = (const int*)d_in[11];
    const int*   feas = (const int*)d_in[12];
    float* out = (float*)d_out;

    // workspace layout (floats): ~3.4 MB total
    float* ws        = (float*)d_ws;
    float* q1_ws     = ws;                       // B*D
    float* q2_ws     = q1_ws + B * D;            // B*D
    int*   mask_ws   = (int*)(q2_ws + B * D);    // B*N ints
    float* out1_ws   = (float*)(mask_ws + B * N);// B*D
    float* out2_ws   = out1_ws + B * D;          // B*D
    float* glimpse_ws= out2_ws + B * D;          // B*D
    float* logits_ws = glimpse_ws + B * D;       // B*N

    hipLaunchKernelGGL(k_ctx, dim3(B / 4), dim3(256), 0, stream,
                       ne, gc, cap, dem, rem, Wctx, head, feas,
                       mask_ws, q1_ws, q2_ws);
    hipLaunchKernelGGL(k_attn, dim3(B * H), dim3(256), 0, stream,
                       gk, gvv, q1_ws, q2_ws, mask_ws, out1_ws, out2_ws);
    hipLaunchKernelGGL(k_proj, dim3(B / 4), dim3(256), 0, stream,
                       out1_ws, out2_ws, Wout, Wsa, glimpse_ws, out + B * N);
    hipLaunchKernelGGL(k_logits, dim3(B * 4), dim3(256), 0, stream,
                       lk, glimpse_ws, mask_ws, logits_ws);
    hipLaunchKernelGGL(k_logsoftmax, dim3(B), dim3(256), 0, stream,
                       logits_ws, out);
}

// Round 2
// 875.575 us; speedup vs baseline: 1.3809x; 1.3809x over previous
//
#include <hip/hip_runtime.h>
#include <math.h>

#define B 256
#define N 1000
#define D 256
#define H 8
#define DH 32
#define NEG (-1000000000.0f)

__device__ __forceinline__ float waveReduceMax(float v) {
#pragma unroll
    for (int off = 32; off >= 1; off >>= 1) v = fmaxf(v, __shfl_xor(v, off, 64));
    return v;
}
__device__ __forceinline__ float waveReduceSum(float v) {
#pragma unroll
    for (int off = 32; off >= 1; off >>= 1) v += __shfl_xor(v, off, 64);
    return v;
}

// ---------------------------------------------------------------------------
// K0: mask fix — mask[:,0] |= !any(mask).  One block per batch.
// ---------------------------------------------------------------------------
__global__ __launch_bounds__(256) void k_mask(
    const int* __restrict__ feas, int* __restrict__ mask_ws)
{
    __shared__ int sRed[4];
    const int b = blockIdx.x;
    const int tid = threadIdx.x;
    int vals[4];
    int orloc = 0;
#pragma unroll
    for (int k = 0; k < 4; ++k) {
        int n = tid + k * 256;
        int v = (n < N) ? feas[b * N + n] : 0;
        vals[k] = v;
        orloc |= v;
    }
#pragma unroll
    for (int off = 32; off >= 1; off >>= 1) orloc |= __shfl_xor(orloc, off, 64);
    if ((tid & 63) == 0) sRed[tid >> 6] = orloc;
    __syncthreads();
    const int anyf = sRed[0] | sRed[1] | sRed[2] | sRed[3];
#pragma unroll
    for (int k = 0; k < 4; ++k) {
        int n = tid + k * 256;
        if (n < N) {
            int m = vals[k];
            if (n == 0 && !anyf) m = 1;
            mask_ws[b * N + n] = m;
        }
    }
}

// ---------------------------------------------------------------------------
// K1: step_context GEMV.  grid 512 = (b, col-half).  thread j -> one output col.
// ---------------------------------------------------------------------------
__global__ __launch_bounds__(256) void k_ctx(
    const float* __restrict__ ne, const float* __restrict__ gc,
    const float* __restrict__ cap, const float* __restrict__ dem,
    const float* __restrict__ rem, const float* __restrict__ Wctx,
    const int* __restrict__ head,
    float* __restrict__ q1_ws, float* __restrict__ q2_ws)
{
    __shared__ float xs[515];
    const int tid = threadIdx.x;
    const int b = blockIdx.x >> 1;
    const int half = blockIdx.x & 1;
    const int hd = head[b];
    for (int i = tid; i < 515; i += 256) {
        float v;
        if (i < 256)       v = ne[(size_t)(b * N + hd) * D + i];
        else if (i < 512)  v = gc[b * D + (i - 256)];
        else if (i == 512) v = cap[b];
        else if (i == 513) v = dem[b];
        else               v = rem[b];
        xs[i] = v;
    }
    __syncthreads();
    const float* __restrict__ wcol = Wctx + half * 256 + tid;
    float a = 0.f;
#pragma unroll 5
    for (int i = 0; i < 515; ++i) a = fmaf(xs[i], wcol[i * 512], a);
    (half ? q2_ws : q1_ws)[b * D + tid] = a;
}

// ---------------------------------------------------------------------------
// K2: dual-query masked attention per (b,h).  Fully coalesced K/V passes:
// lane = n_sub*8 + d4 -> 8 consecutive rows x 8 float4 = contiguous 1KB/wave.
// ---------------------------------------------------------------------------
__global__ __launch_bounds__(256) void k_attn(
    const float* __restrict__ gk, const float* __restrict__ gv,
    const float* __restrict__ q1_ws, const float* __restrict__ q2_ws,
    const int* __restrict__ mask_ws,
    float* __restrict__ out1_ws, float* __restrict__ out2_ws)
{
    __shared__ float s1[N];
    __shared__ float s2[N];
    __shared__ int smask[N];
    __shared__ __align__(16) float qsh[2][DH];
    __shared__ float redA[4], redB[4];
    __shared__ __align__(16) float part1[4][DH];
    __shared__ __align__(16) float part2[4][DH];

    const int tid = threadIdx.x;
    const int b = blockIdx.x >> 3;
    const int h = blockIdx.x & 7;
    const int wid = tid >> 6;
    const int lane = tid & 63;
    const int nsub = lane >> 3;   // 0..7  (row within wave's 8-row chunk)
    const int d4 = lane & 7;      // 0..7  (float4 within row)

    for (int i = tid; i < N; i += 256) smask[i] = mask_ws[b * N + i];
    if (tid < 64) {
        int set = tid >> 5, d = tid & 31;
        qsh[set][d] = (set ? q2_ws : q1_ws)[b * D + h * DH + d];
    }
    __syncthreads();

    const float4 q1v = ((const float4*)qsh[0])[d4];
    const float4 q2v = ((const float4*)qsh[1])[d4];
    const float scale = 0.17677669529663687f; // 1/sqrt(32)
    const float4* __restrict__ kb = (const float4*)(gk + (size_t)(b * H + h) * N * DH);

    // ---- phase 1: scores (coalesced K pass) ----
    for (int base = 0; base < N; base += 32) {
        int row = base + wid * 8 + nsub;
        if (row < N) {
            float4 kv = kb[row * 8 + d4];
            float d1 = kv.x * q1v.x + kv.y * q1v.y + kv.z * q1v.z + kv.w * q1v.w;
            float d2 = kv.x * q2v.x + kv.y * q2v.y + kv.z * q2v.z + kv.w * q2v.w;
            d1 += __shfl_xor(d1, 1, 64); d1 += __shfl_xor(d1, 2, 64); d1 += __shfl_xor(d1, 4, 64);
            d2 += __shfl_xor(d2, 1, 64); d2 += __shfl_xor(d2, 2, 64); d2 += __shfl_xor(d2, 4, 64);
            if (d4 == 0) {
                int m = smask[row];
                s1[row] = m ? d1 * scale : NEG;
                s2[row] = m ? d2 * scale : NEG;
            }
        }
    }
    __syncthreads();

    // ---- phase 2: masked softmax over LDS scores ----
    float m1 = -INFINITY, m2 = -INFINITY;
#pragma unroll
    for (int k = 0; k < 4; ++k) {
        int n = tid + k * 256;
        if (n < N) { m1 = fmaxf(m1, s1[n]); m2 = fmaxf(m2, s2[n]); }
    }
    m1 = waveReduceMax(m1);
    m2 = waveReduceMax(m2);
    if ((tid & 63) == 0) { redA[tid >> 6] = m1; redB[tid >> 6] = m2; }
    __syncthreads();
    m1 = fmaxf(fmaxf(redA[0], redA[1]), fmaxf(redA[2], redA[3]));
    m2 = fmaxf(fmaxf(redB[0], redB[1]), fmaxf(redB[2], redB[3]));
    __syncthreads();

    float sum1 = 0.f, sum2 = 0.f;
#pragma unroll
    for (int k = 0; k < 4; ++k) {
        int n = tid + k * 256;
        if (n < N) {
            float e1 = __expf(s1[n] - m1);
            float e2 = __expf(s2[n] - m2);
            s1[n] = e1; s2[n] = e2;
            sum1 += e1; sum2 += e2;
        }
    }
    sum1 = waveReduceSum(sum1);
    sum2 = waveReduceSum(sum2);
    if ((tid & 63) == 0) { redA[tid >> 6] = sum1; redB[tid >> 6] = sum2; }
    __syncthreads();
    sum1 = redA[0] + redA[1] + redA[2] + redA[3];
    sum2 = redB[0] + redB[1] + redB[2] + redB[3];

    // ---- phase 3: attn @ V (coalesced V pass) ----
    const float4* __restrict__ vb = (const float4*)(gv + (size_t)(b * H + h) * N * DH);
    float4 a1 = {0.f, 0.f, 0.f, 0.f}, a2 = {0.f, 0.f, 0.f, 0.f};
    for (int base = 0; base < N; base += 32) {
        int row = base + wid * 8 + nsub;
        if (row < N) {
            float4 vv = vb[row * 8 + d4];
            float p1 = s1[row], p2 = s2[row];
            a1.x = fmaf(p1, vv.x, a1.x); a1.y = fmaf(p1, vv.y, a1.y);
            a1.z = fmaf(p1, vv.z, a1.z); a1.w = fmaf(p1, vv.w, a1.w);
            a2.x = fmaf(p2, vv.x, a2.x); a2.y = fmaf(p2, vv.y, a2.y);
            a2.z = fmaf(p2, vv.z, a2.z); a2.w = fmaf(p2, vv.w, a2.w);
        }
    }
    // reduce across the 8 n_sub groups (lanes sharing d4)
#pragma unroll
    for (int off = 8; off <= 32; off <<= 1) {
        a1.x += __shfl_xor(a1.x, off, 64); a1.y += __shfl_xor(a1.y, off, 64);
        a1.z += __shfl_xor(a1.z, off, 64); a1.w += __shfl_xor(a1.w, off, 64);
        a2.x += __shfl_xor(a2.x, off, 64); a2.y += __shfl_xor(a2.y, off, 64);
        a2.z += __shfl_xor(a2.z, off, 64); a2.w += __shfl_xor(a2.w, off, 64);
    }
    if (lane < 8) {
        ((float4*)part1[wid])[d4] = a1;
        ((float4*)part2[wid])[d4] = a2;
    }
    __syncthreads();

    if (tid < 64) {
        int set = tid >> 5, d = tid & 31;
        float tot = set ? (part2[0][d] + part2[1][d] + part2[2][d] + part2[3][d])
                        : (part1[0][d] + part1[1][d] + part1[2][d] + part1[3][d]);
        float rs = 1.f / (set ? sum2 : sum1);
        (set ? out2_ws : out1_ws)[b * D + h * DH + d] = tot * rs;
    }
}

// ---------------------------------------------------------------------------
// K3: glimpse = out1 @ W_out ; head_encoding = out2 @ W_sa
// grid 512 = (b, which).  thread j -> one output col.
// ---------------------------------------------------------------------------
__global__ __launch_bounds__(256) void k_proj(
    const float* __restrict__ out1_ws, const float* __restrict__ out2_ws,
    const float* __restrict__ Wout, const float* __restrict__ Wsa,
    float* __restrict__ glimpse_ws, float* __restrict__ head_enc)
{
    __shared__ float x[D];
    const int tid = threadIdx.x;
    const int b = blockIdx.x >> 1;
    const int which = blockIdx.x & 1;
    const float* __restrict__ src = which ? out2_ws : out1_ws;
    x[tid] = src[b * D + tid];
    __syncthreads();
    const float* __restrict__ W = which ? Wsa : Wout;
    float a = 0.f;
#pragma unroll 8
    for (int i = 0; i < D; ++i) a = fmaf(x[i], W[i * D + tid], a);
    (which ? head_enc : glimpse_ws)[b * D + tid] = a;
}

// ---------------------------------------------------------------------------
// K4: logits GEMV, wave-per-row, unrolled x2 for load/shuffle overlap.
// grid B*4 blocks (250 rows each), 256 threads (4 waves)
// ---------------------------------------------------------------------------
__global__ __launch_bounds__(256) void k_logits(
    const float* __restrict__ lk, const float* __restrict__ glimpse_ws,
    const int* __restrict__ mask_ws, float* __restrict__ logits_ws)
{
    __shared__ __align__(16) float gsh[D];
    const int tid = threadIdx.x;
    const int b = blockIdx.x >> 2;
    const int chunk = blockIdx.x & 3;
    gsh[tid] = glimpse_ws[b * D + tid];
    __syncthreads();

    const int lane = tid & 63, wid = tid >> 6;
    const float4 gv = ((const float4*)gsh)[lane];
    const int n0 = chunk * 250;
    const int nend = n0 + 250;
    for (int n = n0 + wid; n < nend; n += 8) {
        const int n2 = n + 4;
        const bool has2 = (n2 < nend);
        float4 k1 = ((const float4*)(lk + (size_t)(b * N + n) * D))[lane];
        float4 k2 = has2 ? ((const float4*)(lk + (size_t)(b * N + n2) * D))[lane]
                         : make_float4(0.f, 0.f, 0.f, 0.f);
        float p1 = k1.x * gv.x + k1.y * gv.y + k1.z * gv.z + k1.w * gv.w;
        float p2 = k2.x * gv.x + k2.y * gv.y + k2.z * gv.z + k2.w * gv.w;
#pragma unroll
        for (int off = 32; off >= 1; off >>= 1) {
            p1 += __shfl_xor(p1, off, 64);
            p2 += __shfl_xor(p2, off, 64);
        }
        if (lane == 0) {
            float l1 = 10.0f * tanhf(p1 * 0.0625f);
            logits_ws[b * N + n] = mask_ws[b * N + n] ? l1 : NEG;
            if (has2) {
                float l2 = 10.0f * tanhf(p2 * 0.0625f);
                logits_ws[b * N + n2] = mask_ws[b * N + n2] ? l2 : NEG;
            }
        }
    }
}

// ---------------------------------------------------------------------------
// K5: log_softmax over each row of logits.  grid B blocks.
// ---------------------------------------------------------------------------
__global__ __launch_bounds__(256) void k_logsoftmax(
    const float* __restrict__ logits_ws, float* __restrict__ logp)
{
    __shared__ float red[4];
    const int tid = threadIdx.x;
    const int b = blockIdx.x;
    float v[4];
    float m = -INFINITY;
#pragma unroll
    for (int k = 0; k < 4; ++k) {
        int n = tid + k * 256;
        v[k] = (n < N) ? logits_ws[b * N + n] : -INFINITY;
        m = fmaxf(m, v[k]);
    }
    m = waveReduceMax(m);
    if ((tid & 63) == 0) red[tid >> 6] = m;
    __syncthreads();
    m = fmaxf(fmaxf(red[0], red[1]), fmaxf(red[2], red[3]));
    __syncthreads();
    float s = 0.f;
#pragma unroll
    for (int k = 0; k < 4; ++k) {
        int n = tid + k * 256;
        if (n < N) s += __expf(v[k] - m);
    }
    s = waveReduceSum(s);
    if ((tid & 63) == 0) red[tid >> 6] = s;
    __syncthreads();
    s = red[0] + red[1] + red[2] + red[3];
    const float lse = m + logf(s);
#pragma unroll
    for (int k = 0; k < 4; ++k) {
        int n = tid + k * 256;
        if (n < N) logp[b * N + n] = v[k] - lse;
    }
}

extern "C" void kernel_launch(void* const* d_in, const int* in_sizes, int n_in,
                              void* d_out, int out_size, void* d_ws, size_t ws_size,
                              hipStream_t stream) {
    const float* ne   = (const float*)d_in[0];
    const float* gc   = (const float*)d_in[1];
    const float* gk   = (const float*)d_in[2];
    const float* gvv  = (const float*)d_in[3];
    const float* lk   = (const float*)d_in[4];
    const float* cap  = (const float*)d_in[5];
    const float* dem  = (const float*)d_in[6];
    const float* rem  = (const float*)d_in[7];
    const float* Wctx = (const float*)d_in[8];
    const float* Wout = (const float*)d_in[9];
    const float* Wsa  = (const float*)d_in[10];
    const int*   head = (const int*)d_in[11];
    const int*   feas = (const int*)d_in[12];
    float* out = (float*)d_out;

    float* ws        = (float*)d_ws;
    float* q1_ws     = ws;                        // B*D
    float* q2_ws     = q1_ws + B * D;             // B*D
    int*   mask_ws   = (int*)(q2_ws + B * D);     // B*N ints
    float* out1_ws   = (float*)(mask_ws + B * N); // B*D
    float* out2_ws   = out1_ws + B * D;           // B*D
    float* glimpse_ws= out2_ws + B * D;           // B*D
    float* logits_ws = glimpse_ws + B * D;        // B*N

    hipLaunchKernelGGL(k_mask, dim3(B), dim3(256), 0, stream, feas, mask_ws);
    hipLaunchKernelGGL(k_ctx, dim3(B * 2), dim3(256), 0, stream,
                       ne, gc, cap, dem, rem, Wctx, head, q1_ws, q2_ws);
    hipLaunchKernelGGL(k_attn, dim3(B * H), dim3(256), 0, stream,
                       gk, gvv, q1_ws, q2_ws, mask_ws, out1_ws, out2_ws);
    hipLaunchKernelGGL(k_proj, dim3(B * 2), dim3(256), 0, stream,
                       out1_ws, out2_ws, Wout, Wsa, glimpse_ws, out + B * N);
    hipLaunchKernelGGL(k_logits, dim3(B * 4), dim3(256), 0, stream,
                       lk, glimpse_ws, mask_ws, logits_ws);
    hipLaunchKernelGGL(k_logsoftmax, dim3(B), dim3(256), 0, stream,
                       logits_ws, out);
}